// Round 4
// baseline (369.275 us; speedup 1.0000x reference)
//
#include <hip/hip_runtime.h>

typedef float f32x4 __attribute__((ext_vector_type(4)));
typedef float f32x16 __attribute__((ext_vector_type(16)));
typedef short bf16x8 __attribute__((ext_vector_type(8)));
typedef unsigned int uint;
typedef unsigned short ushort_t;

#define EMB    512
#define NSEQ   2048
#define NBATCH 4
#define NHEAD  8
#define MROWS  (NBATCH * NSEQ)   // 8192
#define CEXP   0.06375872f       // log2(e) / sqrt(512)

// round-to-nearest-even fp32 -> bf16 (bit trick)
__device__ __forceinline__ uint f2bf(float x) {
    uint u = __builtin_bit_cast(uint, x);
    return (u + 0x7fffu + ((u >> 16) & 1u)) >> 16;
}

// async global->LDS, 16B per lane; LDS dest = wave-uniform base + lane*16
__device__ __forceinline__ void glds16(const void* g, void* l) {
    __builtin_amdgcn_global_load_lds(
        (const __attribute__((address_space(1))) uint*)g,
        (__attribute__((address_space(3))) uint*)l, 16, 0, 0);
}

// ---------------------------------------------------------------------------
// Prep: x -> bf16; Wq|Wk|Wv -> Wqkvb bf16 [1536][512]; biases concat; Wo -> bf16
// ---------------------------------------------------------------------------
__global__ __launch_bounds__(256)
void prep(const float* __restrict__ x,
          const float* __restrict__ Wq, const float* __restrict__ Wk,
          const float* __restrict__ Wv, const float* __restrict__ Wo,
          const float* __restrict__ bq, const float* __restrict__ bk,
          const float* __restrict__ bv,
          ushort_t* __restrict__ xb, ushort_t* __restrict__ Wqkvb,
          float* __restrict__ bqkv, ushort_t* __restrict__ Wob) {
    int t = blockIdx.x * 256 + threadIdx.x;   // f4-group index, 1048576 total
    {
        float4 v = ((const float4*)x)[t];
        uint2 p;
        p.x = f2bf(v.x) | (f2bf(v.y) << 16);
        p.y = f2bf(v.z) | (f2bf(v.w) << 16);
        ((uint2*)xb)[t] = p;
    }
    if (t < 65536) {   // 512*512/4 groups per weight
        float4 a = ((const float4*)Wq)[t];
        float4 b = ((const float4*)Wk)[t];
        float4 c = ((const float4*)Wv)[t];
        float4 d = ((const float4*)Wo)[t];
        uint2 p;
        p.x = f2bf(a.x) | (f2bf(a.y) << 16); p.y = f2bf(a.z) | (f2bf(a.w) << 16);
        ((uint2*)Wqkvb)[t] = p;
        p.x = f2bf(b.x) | (f2bf(b.y) << 16); p.y = f2bf(b.z) | (f2bf(b.w) << 16);
        ((uint2*)Wqkvb)[t + 65536] = p;
        p.x = f2bf(c.x) | (f2bf(c.y) << 16); p.y = f2bf(c.z) | (f2bf(c.w) << 16);
        ((uint2*)Wqkvb)[t + 131072] = p;
        p.x = f2bf(d.x) | (f2bf(d.y) << 16); p.y = f2bf(d.z) | (f2bf(d.w) << 16);
        ((uint2*)Wob)[t] = p;
    }
    if (t < 512) {
        bqkv[t] = bq[t]; bqkv[512 + t] = bk[t]; bqkv[1024 + t] = bv[t];
    }
}

// ---------------------------------------------------------------------------
// GEMM C[8192 x N] = A[8192x512]bf16 * BT[Nx512]bf16 + bias, 128x128 tile,
// BK=32, 4 waves, 16x16x32 mfma, 4x4 subtiles/wave.
// Staging via global_load_lds width=16 (m97 pattern): unpadded [128][32]
// tiles, wave covers 16 rows per 1KB instruction, 2 instructions per matrix.
// MODE 0: QKV (N=1536): n0<1024 -> LDS-transposed coalesced bf16 stores to
//         QKb[8192][1024] (Q cols pre-scaled by CEXP);
//         n0>=1024 -> transposed packed stores to VTg[2048][2048].
// MODE 1: out proj (N=512): LDS-transposed coalesced fp32 stores + bias.
// ---------------------------------------------------------------------------
template<int MODE>
__global__ __launch_bounds__(256)
void gemm128(const ushort_t* __restrict__ A, const ushort_t* __restrict__ BT,
             const float* __restrict__ bias, ushort_t* __restrict__ oQK,
             ushort_t* __restrict__ oVT, float* __restrict__ oC) {
    __shared__ ushort_t As[128][32];   // 8 KB, unpadded (glds layout constraint)
    __shared__ ushort_t Bs[128][32];
    __shared__ float ep[32][132];      // epilogue transpose buffer (16.9 KB)
    const int tid = threadIdx.x, wave = tid >> 6, lane = tid & 63;
    const int m0 = blockIdx.x * 128, n0 = blockIdx.y * 128;
    const int wr = (wave & 1) * 64, wc = (wave >> 1) * 64;

    f32x4 acc[4][4];
#pragma unroll
    for (int i = 0; i < 4; ++i)
#pragma unroll
        for (int j = 0; j < 4; ++j) acc[i][j] = (f32x4){0.f, 0.f, 0.f, 0.f};

    // per-lane global source: row = wave*16 + lane/4, col-seg = (lane&3)*16B
    const int grow = wave * 16 + (lane >> 2);
    const int gcol = (lane & 3) * 8;
    const ushort_t* Ag = A  + (size_t)(m0 + grow) * 512 + gcol;
    const ushort_t* Bg = BT + (size_t)(n0 + grow) * 512 + gcol;
    ushort_t* lA0 = &As[wave * 16][0];
    ushort_t* lA1 = &As[64 + wave * 16][0];
    ushort_t* lB0 = &Bs[wave * 16][0];
    ushort_t* lB1 = &Bs[64 + wave * 16][0];
    const int fr = lane & 15, fc = (lane >> 4) * 8;

    for (int kt = 0; kt < 16; ++kt) {
        __syncthreads();   // prior frag reads done before overwrite
        glds16(Ag + kt * 32,             lA0);
        glds16(Ag + kt * 32 + 64 * 512,  lA1);
        glds16(Bg + kt * 32,             lB0);
        glds16(Bg + kt * 32 + 64 * 512,  lB1);
        __syncthreads();   // vmcnt(0) drained -> tiles visible
        bf16x8 af[4], bf[4];
#pragma unroll
        for (int i = 0; i < 4; ++i) af[i] = *(const bf16x8*)&As[wr + i * 16 + fr][fc];
#pragma unroll
        for (int j = 0; j < 4; ++j) bf[j] = *(const bf16x8*)&Bs[wc + j * 16 + fr][fc];
#pragma unroll
        for (int i = 0; i < 4; ++i)
#pragma unroll
            for (int j = 0; j < 4; ++j)
                acc[i][j] = __builtin_amdgcn_mfma_f32_16x16x32_bf16(af[i], bf[j], acc[i][j], 0, 0, 0);
    }

    const int col_l = lane & 15, row_l = (lane >> 4) * 4;

    if (MODE == 0 && n0 >= 1024) {
        // V part: direct transposed packed stores
#pragma unroll
        for (int j = 0; j < 4; ++j) {
            const int col = n0 + wc + j * 16 + col_l;
            const float bv = bias[col];
#pragma unroll
            for (int i = 0; i < 4; ++i) {
                const int row = m0 + wr + i * 16 + row_l;
                f32x4 v = acc[i][j];
                v += (f32x4){bv, bv, bv, bv};
                const int e = col - 1024;
                const int b = row >> 11, tok = row & 2047;
                uint2 p;
                p.x = f2bf(v[0]) | (f2bf(v[1]) << 16);
                p.y = f2bf(v[2]) | (f2bf(v[3]) << 16);
                *(uint2*)&oVT[((size_t)(b * 512 + e)) * 2048 + tok] = p;
            }
        }
        return;
    }

    // LDS-transposed coalesced epilogue (QK bf16 / out-proj fp32)
    const float scale = (MODE == 0 && n0 < 512) ? CEXP : 1.0f;
    float bv[4];
#pragma unroll
    for (int j = 0; j < 4; ++j) bv[j] = bias[n0 + wc + j * 16 + col_l];

    const int erow = tid >> 3, eseg = (tid & 7) * 16;
#pragma unroll
    for (int c = 0; c < 4; ++c) {
        __syncthreads();
        if (wr == (c >> 1) * 64) {
#pragma unroll
            for (int ii = 0; ii < 2; ++ii) {
                const int i = (c & 1) * 2 + ii;
#pragma unroll
                for (int j = 0; j < 4; ++j) {
                    f32x4 v = acc[i][j];
#pragma unroll
                    for (int r = 0; r < 4; ++r)
                        ep[ii * 16 + row_l + r][wc + j * 16 + col_l] = (v[r] + bv[j]) * scale;
                }
            }
        }
        __syncthreads();
        const int grow2 = m0 + c * 32 + erow;
        if (MODE == 0) {
            uint4 o0, o1;
#pragma unroll
            for (int k = 0; k < 4; ++k) {
                uint lo = f2bf(ep[erow][eseg + k * 2])     | (f2bf(ep[erow][eseg + k * 2 + 1]) << 16);
                uint hi = f2bf(ep[erow][eseg + 8 + k * 2]) | (f2bf(ep[erow][eseg + 9 + k * 2]) << 16);
                ((uint*)&o0)[k] = lo; ((uint*)&o1)[k] = hi;
            }
            *(uint4*)&oQK[(size_t)grow2 * 1024 + n0 + eseg]     = o0;
            *(uint4*)&oQK[(size_t)grow2 * 1024 + n0 + eseg + 8] = o1;
        } else {
#pragma unroll
            for (int k = 0; k < 4; ++k) {
                f32x4 v = *(const f32x4*)&ep[erow][eseg + k * 4];
                *(f32x4*)&oC[(size_t)grow2 * 512 + n0 + eseg + k * 4] = v;
            }
        }
    }
}

// ---------------------------------------------------------------------------
// MFMA flash attention, O^T formulation: no P LDS round-trip.
// Block = 64 q-rows x (b,h) x kslice, 128 threads (2 waves); wave w owns
// q-rows [w*32, w*32+32), Q B-frags in registers. Per 64-krow tile:
//   S^T = K*Q^T (32x32x16, C-layout: qrow=lane&31, krow=(r&3)+8*(r>>2)+4*lhi)
//   P^T = exp2(S^T) trunc-bf16, packed in regs; B-operand frags for
//   O^T += V^T * P^T are built via 8 packs + shfl_xor(32) + cndmask per half
//   (B layout needs krow=(lane>>5)*8+j, qrow=lane&31 -> half-wave swap).
// l sums the truncated P (bias cancellation). Partials stored transposed
// Opart[slice][bh*64+d][tok] (coalesced), combined by combine2T.
// ---------------------------------------------------------------------------
template<int NSLICE>
__global__ __launch_bounds__(128)
void attn_mfma(const ushort_t* __restrict__ QK, const ushort_t* __restrict__ VT,
               float* __restrict__ Op, float* __restrict__ Lp,
               ushort_t* __restrict__ AO) {
    __shared__ ushort_t Ks[64][72];       // [krow][d]
    __shared__ ushort_t Vs[64][72];       // [d][krow]  (V^T tile)

    const int tid = threadIdx.x, w = tid >> 6, lane = tid & 63;
    const int qt = blockIdx.x, bh = blockIdx.y, b = bh >> 3, h = bh & 7;
    const int slice = (NSLICE > 1) ? blockIdx.z : 0;
    const int l31 = lane & 31, lhi = lane >> 5;

    // Q B-frags (pre-scaled by CEXP in gemm epilogue)
    const int tok = qt * 64 + w * 32 + l31;
    const size_t qrow = (size_t)(b * NSEQ + tok);
    bf16x8 qf[4];
#pragma unroll
    for (int ks = 0; ks < 4; ++ks)
        qf[ks] = *(const bf16x8*)&QK[qrow * 1024 + h * 64 + ks * 16 + lhi * 8];

    f32x16 accO[2];
#pragma unroll
    for (int i = 0; i < 16; ++i) { accO[0][i] = 0.f; accO[1][i] = 0.f; }
    float lpart = 0.f;

    const int sr = tid & 63, sc = (tid >> 6) * 32;   // staging: row, 32-ushort seg
    const ushort_t* Kg = QK + (size_t)(b * NSEQ) * 1024 + 512 + h * 64;
    const ushort_t* Vg = VT + ((size_t)(b * 512 + h * 64)) * 2048;

    const int kt0 = slice * (32 / NSLICE), kt1 = kt0 + 32 / NSLICE;
    for (int kt = kt0; kt < kt1; ++kt) {
        const int k0 = kt * 64;
        uint4 kv[4], vv[4];
#pragma unroll
        for (int k = 0; k < 4; ++k) {
            kv[k] = *(const uint4*)&Kg[(size_t)(k0 + sr) * 1024 + sc + 8 * k];
            vv[k] = *(const uint4*)&Vg[(size_t)sr * 2048 + k0 + sc + 8 * k];
        }
        __syncthreads();
#pragma unroll
        for (int k = 0; k < 4; ++k) {
            *(uint4*)&Ks[sr][sc + 8 * k] = kv[k];
            *(uint4*)&Vs[sr][sc + 8 * k] = vv[k];
        }
        __syncthreads();

#pragma unroll
        for (int ms = 0; ms < 2; ++ms) {   // krow halves 0..31 / 32..63
            // S^T half: A = K rows [ms*32 + l31], B = Q^T
            f32x16 st;
#pragma unroll
            for (int i = 0; i < 16; ++i) st[i] = 0.f;
#pragma unroll
            for (int ks = 0; ks < 4; ++ks) {
                bf16x8 ka = *(const bf16x8*)&Ks[ms * 32 + l31][ks * 16 + lhi * 8];
                st = __builtin_amdgcn_mfma_f32_32x32x16_bf16(ka, qf[ks], st, 0, 0, 0);
            }
            // P^T: exp2, truncate to bf16, pack pairs; l sums truncated values
            uint dd[8], ee[8];
#pragma unroll
            for (int i = 0; i < 8; ++i) {
                uint ua = __builtin_bit_cast(uint, __builtin_amdgcn_exp2f(st[2 * i]));
                uint ub = __builtin_bit_cast(uint, __builtin_amdgcn_exp2f(st[2 * i + 1]));
                lpart += __builtin_bit_cast(float, ua & 0xffff0000u)
                       + __builtin_bit_cast(float, ub & 0xffff0000u);
                dd[i] = (ua >> 16) | (ub & 0xffff0000u);
            }
#pragma unroll
            for (int i = 0; i < 8; ++i) ee[i] = (uint)__shfl_xor((int)dd[i], 32);
            // dd[i] covers krow pair (16*(i>>2)*? ) per C-layout; build B-frags
#pragma unroll
            for (int s = 0; s < 2; ++s) {
                union { uint u[4]; bf16x8 v; } B;
                B.u[0] = lhi ? ee[4 * s + 2] : dd[4 * s + 0];
                B.u[1] = lhi ? ee[4 * s + 3] : dd[4 * s + 1];
                B.u[2] = lhi ? dd[4 * s + 2] : ee[4 * s + 0];
                B.u[3] = lhi ? dd[4 * s + 3] : ee[4 * s + 1];
                const int step = ms * 2 + s;   // 16-krow MFMA step within tile
                bf16x8 va0 = *(const bf16x8*)&Vs[l31][step * 16 + lhi * 8];
                bf16x8 va1 = *(const bf16x8*)&Vs[32 + l31][step * 16 + lhi * 8];
                accO[0] = __builtin_amdgcn_mfma_f32_32x32x16_bf16(va0, B.v, accO[0], 0, 0, 0);
                accO[1] = __builtin_amdgcn_mfma_f32_32x32x16_bf16(va1, B.v, accO[1], 0, 0, 0);
            }
        }
    }

    // full l per qrow: halves of krows split across lane^32 pairs
    const float lfull = lpart + __shfl_xor(lpart, 32);

    if (NSLICE == 1) {
        const float inv = 1.0f / lfull;
#pragma unroll
        for (int hf = 0; hf < 2; ++hf)
#pragma unroll
            for (int r = 0; r < 16; ++r) {
                const int d = (r & 3) + 8 * (r >> 2) + 4 * lhi + 32 * hf;
                AO[((size_t)(b * NSEQ + tok)) * 512 + h * 64 + d] =
                    (ushort_t)f2bf(accO[hf][r] * inv);
            }
    } else {
        if (lane < 32) Lp[(size_t)slice * 65536 + bh * 2048 + tok] = lfull;
        float* Os = Op + (size_t)slice * 4194304;
#pragma unroll
        for (int hf = 0; hf < 2; ++hf)
#pragma unroll
            for (int r = 0; r < 16; ++r) {
                const int d = (r & 3) + 8 * (r >> 2) + 4 * lhi + 32 * hf;
                Os[((size_t)(bh * 64 + d)) * 2048 + tok] = accO[hf][r];
            }
    }
}

// ---------------------------------------------------------------------------
// Combine split-K partials (transposed layout): AO[tok][e] = sum_s O_s / sum_s l_s.
// Reads Opart[s][bh*64+d][tok] coalesced, LDS-transposes 64x64, writes
// row-major bf16 coalesced.
// ---------------------------------------------------------------------------
__global__ __launch_bounds__(256)
void combine2T(const float* __restrict__ Op, const float* __restrict__ Lp,
               ushort_t* __restrict__ AO) {
    __shared__ float T[64][68];
    const int tid = threadIdx.x;
    const int tc = blockIdx.x, bh = blockIdx.y;
    const int b = bh >> 3, h = bh & 7;
    const int tok0 = tc * 64;

    const int d = tid >> 2, ts = (tid & 3) * 16;
    const float* P0 = Op + ((size_t)(bh * 64 + d)) * 2048 + tok0 + ts;
    const float* P1 = P0 + 4194304;
#pragma unroll
    for (int k = 0; k < 4; ++k) {
        f32x4 a = *(const f32x4*)(P0 + 4 * k);
        f32x4 c = *(const f32x4*)(P1 + 4 * k);
        *(f32x4*)&T[d][ts + 4 * k] = a + c;
    }
    __syncthreads();

    const int tk = tid >> 2, ds = (tid & 3) * 16;
    const int tok = tok0 + tk;
    const float inv = 1.0f / (Lp[bh * 2048 + tok] + Lp[65536 + bh * 2048 + tok]);
    uint o[8];
#pragma unroll
    for (int k = 0; k < 8; ++k) {
        float a = T[ds + 2 * k][tk] * inv;
        float c = T[ds + 2 * k + 1][tk] * inv;
        o[k] = f2bf(a) | (f2bf(c) << 16);
    }
    ushort_t* dst = AO + ((size_t)(b * NSEQ + tok)) * 512 + h * 64 + ds;
    *(uint4*)dst       = *(const uint4*)&o[0];
    *(uint4*)(dst + 8) = *(const uint4*)&o[4];
}

// ---------------------------------------------------------------------------
extern "C" void kernel_launch(void* const* d_in, const int* in_sizes, int n_in,
                              void* d_out, int out_size, void* d_ws, size_t ws_size,
                              hipStream_t stream) {
    const float* x  = (const float*)d_in[0];
    const float* Wq = (const float*)d_in[1];
    const float* bq = (const float*)d_in[2];
    const float* Wk = (const float*)d_in[3];
    const float* bk = (const float*)d_in[4];
    const float* Wv = (const float*)d_in[5];
    const float* bv = (const float*)d_in[6];
    const float* Wo = (const float*)d_in[7];
    const float* bo = (const float*)d_in[8];

    char* ws = (char*)d_ws;
    ushort_t* xb    = (ushort_t*)(ws);                       //  8,388,608 B
    ushort_t* Wqkvb = (ushort_t*)(ws + 8388608);             //  1,572,864 B
    ushort_t* Wob   = (ushort_t*)(ws + 9961472);             //    524,288 B
    float*    bqkv  = (float*)   (ws + 10485760);            //      6,144 B
    ushort_t* QKb   = (ushort_t*)(ws + 10491904);            // 16,777,216 B
    ushort_t* VTg   = (ushort_t*)(ws + 27269120);            //  8,388,608 B
    ushort_t* AOb   = (ushort_t*)(ws + 35657728);            //  8,388,608 B
    float*    Opart = (float*)   (ws + 44046336);            // 33,554,432 B
    float*    Lpart = (float*)   (ws + 77600768);            //    524,288 B
    const bool split = ws_size >= 78125056;

    prep<<<4096, 256, 0, stream>>>(x, Wq, Wk, Wv, Wo, bq, bk, bv,
                                   xb, Wqkvb, bqkv, Wob);
    gemm128<0><<<dim3(64, 12), 256, 0, stream>>>(xb, Wqkvb, bqkv, QKb, VTg, nullptr);
    if (split) {
        attn_mfma<2><<<dim3(32, 32, 2), 128, 0, stream>>>(QKb, VTg, Opart, Lpart, nullptr);
        combine2T<<<dim3(32, 32), 256, 0, stream>>>(Opart, Lpart, AOb);
    } else {
        attn_mfma<1><<<dim3(32, 32, 1), 128, 0, stream>>>(QKb, VTg, nullptr, nullptr, AOb);
    }
    gemm128<1><<<dim3(64, 4), 256, 0, stream>>>(AOb, Wob, bo, nullptr, nullptr, (float*)d_out);
}

// Round 5
// 187.545 us; speedup vs baseline: 1.9690x; 1.9690x over previous
//
#include <hip/hip_runtime.h>

typedef float f32x4 __attribute__((ext_vector_type(4)));
typedef float f32x16 __attribute__((ext_vector_type(16)));
typedef short bf16x8 __attribute__((ext_vector_type(8)));
typedef unsigned int uint;
typedef unsigned short ushort_t;

#define EMB    512
#define NSEQ   2048
#define NBATCH 4
#define NHEAD  8
#define MROWS  (NBATCH * NSEQ)   // 8192
#define CEXP   0.06375872f       // log2(e) / sqrt(512)

// round-to-nearest-even fp32 -> bf16 (bit trick)
__device__ __forceinline__ uint f2bf(float x) {
    uint u = __builtin_bit_cast(uint, x);
    return (u + 0x7fffu + ((u >> 16) & 1u)) >> 16;
}

// async global->LDS, 16B per lane; LDS dest = wave-uniform base + lane*16
__device__ __forceinline__ void glds16(const void* g, void* l) {
    __builtin_amdgcn_global_load_lds(
        (const __attribute__((address_space(1))) uint*)g,
        (__attribute__((address_space(3))) uint*)l, 16, 0, 0);
}

// ---------------------------------------------------------------------------
// Prep: x -> bf16; Wq|Wk|Wv -> Wqkvb bf16 [1536][512]; biases concat; Wo -> bf16
// ---------------------------------------------------------------------------
__global__ __launch_bounds__(256)
void prep(const float* __restrict__ x,
          const float* __restrict__ Wq, const float* __restrict__ Wk,
          const float* __restrict__ Wv, const float* __restrict__ Wo,
          const float* __restrict__ bq, const float* __restrict__ bk,
          const float* __restrict__ bv,
          ushort_t* __restrict__ xb, ushort_t* __restrict__ Wqkvb,
          float* __restrict__ bqkv, ushort_t* __restrict__ Wob) {
    int t = blockIdx.x * 256 + threadIdx.x;   // f4-group index, 1048576 total
    {
        float4 v = ((const float4*)x)[t];
        uint2 p;
        p.x = f2bf(v.x) | (f2bf(v.y) << 16);
        p.y = f2bf(v.z) | (f2bf(v.w) << 16);
        ((uint2*)xb)[t] = p;
    }
    if (t < 65536) {   // 512*512/4 groups per weight
        float4 a = ((const float4*)Wq)[t];
        float4 b = ((const float4*)Wk)[t];
        float4 c = ((const float4*)Wv)[t];
        float4 d = ((const float4*)Wo)[t];
        uint2 p;
        p.x = f2bf(a.x) | (f2bf(a.y) << 16); p.y = f2bf(a.z) | (f2bf(a.w) << 16);
        ((uint2*)Wqkvb)[t] = p;
        p.x = f2bf(b.x) | (f2bf(b.y) << 16); p.y = f2bf(b.z) | (f2bf(b.w) << 16);
        ((uint2*)Wqkvb)[t + 65536] = p;
        p.x = f2bf(c.x) | (f2bf(c.y) << 16); p.y = f2bf(c.z) | (f2bf(c.w) << 16);
        ((uint2*)Wqkvb)[t + 131072] = p;
        p.x = f2bf(d.x) | (f2bf(d.y) << 16); p.y = f2bf(d.z) | (f2bf(d.w) << 16);
        ((uint2*)Wob)[t] = p;
    }
    if (t < 512) {
        bqkv[t] = bq[t]; bqkv[512 + t] = bk[t]; bqkv[1024 + t] = bv[t];
    }
}

// ---------------------------------------------------------------------------
// GEMM C[8192 x N] = A[8192x512]bf16 * BT[Nx512]bf16 + bias, 128x128 tile,
// BK=32, 4 waves, 16x16x32 mfma, 4x4 subtiles/wave.
// Staging via global_load_lds width=16 (m97 pattern): unpadded [128][32]
// tiles, wave covers 16 rows per 1KB instruction, 2 instructions per matrix.
// MODE 0: QKV (N=1536): n0<1024 -> LDS-transposed coalesced bf16 stores to
//         QKb[8192][1024] (Q cols pre-scaled by CEXP);
//         n0>=1024 -> transposed packed stores to VTg[2048][2048].
// MODE 1: out proj (N=512): LDS-transposed coalesced fp32 stores + bias.
// ---------------------------------------------------------------------------
template<int MODE>
__global__ __launch_bounds__(256)
void gemm128(const ushort_t* __restrict__ A, const ushort_t* __restrict__ BT,
             const float* __restrict__ bias, ushort_t* __restrict__ oQK,
             ushort_t* __restrict__ oVT, float* __restrict__ oC) {
    __shared__ ushort_t As[128][32];   // 8 KB, unpadded (glds layout constraint)
    __shared__ ushort_t Bs[128][32];
    __shared__ float ep[32][132];      // epilogue transpose buffer (16.9 KB)
    const int tid = threadIdx.x, wave = tid >> 6, lane = tid & 63;
    const int m0 = blockIdx.x * 128, n0 = blockIdx.y * 128;
    const int wr = (wave & 1) * 64, wc = (wave >> 1) * 64;

    f32x4 acc[4][4];
#pragma unroll
    for (int i = 0; i < 4; ++i)
#pragma unroll
        for (int j = 0; j < 4; ++j) acc[i][j] = (f32x4){0.f, 0.f, 0.f, 0.f};

    // per-lane global source: row = wave*16 + lane/4, col-seg = (lane&3)*16B
    const int grow = wave * 16 + (lane >> 2);
    const int gcol = (lane & 3) * 8;
    const ushort_t* Ag = A  + (size_t)(m0 + grow) * 512 + gcol;
    const ushort_t* Bg = BT + (size_t)(n0 + grow) * 512 + gcol;
    ushort_t* lA0 = &As[wave * 16][0];
    ushort_t* lA1 = &As[64 + wave * 16][0];
    ushort_t* lB0 = &Bs[wave * 16][0];
    ushort_t* lB1 = &Bs[64 + wave * 16][0];
    const int fr = lane & 15, fc = (lane >> 4) * 8;

    for (int kt = 0; kt < 16; ++kt) {
        __syncthreads();   // prior frag reads done before overwrite
        glds16(Ag + kt * 32,             lA0);
        glds16(Ag + kt * 32 + 64 * 512,  lA1);
        glds16(Bg + kt * 32,             lB0);
        glds16(Bg + kt * 32 + 64 * 512,  lB1);
        __syncthreads();   // vmcnt(0) drained -> tiles visible
        bf16x8 af[4], bf[4];
#pragma unroll
        for (int i = 0; i < 4; ++i) af[i] = *(const bf16x8*)&As[wr + i * 16 + fr][fc];
#pragma unroll
        for (int j = 0; j < 4; ++j) bf[j] = *(const bf16x8*)&Bs[wc + j * 16 + fr][fc];
#pragma unroll
        for (int i = 0; i < 4; ++i)
#pragma unroll
            for (int j = 0; j < 4; ++j)
                acc[i][j] = __builtin_amdgcn_mfma_f32_16x16x32_bf16(af[i], bf[j], acc[i][j], 0, 0, 0);
    }

    const int col_l = lane & 15, row_l = (lane >> 4) * 4;

    if (MODE == 0 && n0 >= 1024) {
        // V part: direct transposed packed stores
#pragma unroll
        for (int j = 0; j < 4; ++j) {
            const int col = n0 + wc + j * 16 + col_l;
            const float bv = bias[col];
#pragma unroll
            for (int i = 0; i < 4; ++i) {
                const int row = m0 + wr + i * 16 + row_l;
                f32x4 v = acc[i][j];
                v += (f32x4){bv, bv, bv, bv};
                const int e = col - 1024;
                const int b = row >> 11, tok = row & 2047;
                uint2 p;
                p.x = f2bf(v[0]) | (f2bf(v[1]) << 16);
                p.y = f2bf(v[2]) | (f2bf(v[3]) << 16);
                *(uint2*)&oVT[((size_t)(b * 512 + e)) * 2048 + tok] = p;
            }
        }
        return;
    }

    // LDS-transposed coalesced epilogue (QK bf16 / out-proj fp32)
    const float scale = (MODE == 0 && n0 < 512) ? CEXP : 1.0f;
    float bv[4];
#pragma unroll
    for (int j = 0; j < 4; ++j) bv[j] = bias[n0 + wc + j * 16 + col_l];

    const int erow = tid >> 3, eseg = (tid & 7) * 16;
#pragma unroll
    for (int c = 0; c < 4; ++c) {
        __syncthreads();
        if (wr == (c >> 1) * 64) {
#pragma unroll
            for (int ii = 0; ii < 2; ++ii) {
                const int i = (c & 1) * 2 + ii;
#pragma unroll
                for (int j = 0; j < 4; ++j) {
                    f32x4 v = acc[i][j];
#pragma unroll
                    for (int r = 0; r < 4; ++r)
                        ep[ii * 16 + row_l + r][wc + j * 16 + col_l] = (v[r] + bv[j]) * scale;
                }
            }
        }
        __syncthreads();
        const int grow2 = m0 + c * 32 + erow;
        if (MODE == 0) {
            uint4 o0, o1;
#pragma unroll
            for (int k = 0; k < 4; ++k) {
                uint lo = f2bf(ep[erow][eseg + k * 2])     | (f2bf(ep[erow][eseg + k * 2 + 1]) << 16);
                uint hi = f2bf(ep[erow][eseg + 8 + k * 2]) | (f2bf(ep[erow][eseg + 9 + k * 2]) << 16);
                ((uint*)&o0)[k] = lo; ((uint*)&o1)[k] = hi;
            }
            *(uint4*)&oQK[(size_t)grow2 * 1024 + n0 + eseg]     = o0;
            *(uint4*)&oQK[(size_t)grow2 * 1024 + n0 + eseg + 8] = o1;
        } else {
#pragma unroll
            for (int k = 0; k < 4; ++k) {
                f32x4 v = *(const f32x4*)&ep[erow][eseg + k * 4];
                *(f32x4*)&oC[(size_t)grow2 * 512 + n0 + eseg + k * 4] = v;
            }
        }
    }
}

// ---------------------------------------------------------------------------
// MFMA flash attention, O^T formulation (no P LDS round-trip), un-spilled:
// 256 threads / 4 waves, 128-row q-tile, __launch_bounds__(256,4) -> 128-VGPR
// cap (live set ~95 incl. 32 acc in unified file -> no scratch).
// Wave w owns q-rows [w*32, w*32+32); Q B-frags in registers. Per 64-krow
// tile: S^T = K*Q^T (32x32x16, C-layout: qrow=lane&31, krow=(r&3)+8*(r>>2)
// +4*lhi); P^T = exp2(S^T) trunc-bf16 packed in regs; B-frags for
// O^T += V^T * P^T built via pack + shfl_xor(32) half-swap (verified R4).
// l sums truncated P (normalization bias cancels). Partials transposed
// Opart[slice][bh*64+d][tok] (coalesced 128B lines), combined by combine2T.
// ---------------------------------------------------------------------------
template<int NSLICE>
__global__ __launch_bounds__(256, 4)
void attn_mfma(const ushort_t* __restrict__ QK, const ushort_t* __restrict__ VT,
               float* __restrict__ Op, float* __restrict__ Lp,
               ushort_t* __restrict__ AO) {
    __shared__ ushort_t Ks[64][72];       // [krow][d]
    __shared__ ushort_t Vs[64][72];       // [d][krow]  (V^T tile)

    const int tid = threadIdx.x, w = tid >> 6, lane = tid & 63;
    const int qt = blockIdx.x, bh = blockIdx.y, b = bh >> 3, h = bh & 7;
    const int slice = (NSLICE > 1) ? blockIdx.z : 0;
    const int l31 = lane & 31, lhi = lane >> 5;

    // Q B-frags (pre-scaled by CEXP in gemm epilogue)
    const int tok = qt * 128 + w * 32 + l31;
    const size_t qrow = (size_t)(b * NSEQ + tok);
    bf16x8 qf[4];
#pragma unroll
    for (int ks = 0; ks < 4; ++ks)
        qf[ks] = *(const bf16x8*)&QK[qrow * 1024 + h * 64 + ks * 16 + lhi * 8];

    f32x16 accO[2];
#pragma unroll
    for (int i = 0; i < 16; ++i) { accO[0][i] = 0.f; accO[1][i] = 0.f; }
    float lpart = 0.f;

    // staging: 256 threads, 2 x uint4 per matrix per thread
    const int sr = tid & 63, sc = (tid >> 6) * 16;
    const ushort_t* Kg = QK + (size_t)(b * NSEQ) * 1024 + 512 + h * 64;
    const ushort_t* Vg = VT + ((size_t)(b * 512 + h * 64)) * 2048;

    const int kt0 = slice * (32 / NSLICE), kt1 = kt0 + 32 / NSLICE;
    for (int kt = kt0; kt < kt1; ++kt) {
        const int k0 = kt * 64;
        uint4 kv0 = *(const uint4*)&Kg[(size_t)(k0 + sr) * 1024 + sc];
        uint4 kv1 = *(const uint4*)&Kg[(size_t)(k0 + sr) * 1024 + sc + 8];
        uint4 vv0 = *(const uint4*)&Vg[(size_t)sr * 2048 + k0 + sc];
        uint4 vv1 = *(const uint4*)&Vg[(size_t)sr * 2048 + k0 + sc + 8];
        __syncthreads();                          // prior frag reads done
        *(uint4*)&Ks[sr][sc] = kv0;  *(uint4*)&Ks[sr][sc + 8] = kv1;
        *(uint4*)&Vs[sr][sc] = vv0;  *(uint4*)&Vs[sr][sc + 8] = vv1;
        __syncthreads();                          // tiles visible

#pragma unroll
        for (int ms = 0; ms < 2; ++ms) {   // krow halves 0..31 / 32..63
            // S^T half: A = K rows [ms*32 + l31], B = Q^T
            f32x16 st;
#pragma unroll
            for (int i = 0; i < 16; ++i) st[i] = 0.f;
#pragma unroll
            for (int ks = 0; ks < 4; ++ks) {
                bf16x8 ka = *(const bf16x8*)&Ks[ms * 32 + l31][ks * 16 + lhi * 8];
                st = __builtin_amdgcn_mfma_f32_32x32x16_bf16(ka, qf[ks], st, 0, 0, 0);
            }
            // P^T: exp2, truncate to bf16, pack pairs; l sums truncated values
            uint dd[8], ee[8];
#pragma unroll
            for (int i = 0; i < 8; ++i) {
                uint ua = __builtin_bit_cast(uint, __builtin_amdgcn_exp2f(st[2 * i]));
                uint ub = __builtin_bit_cast(uint, __builtin_amdgcn_exp2f(st[2 * i + 1]));
                lpart += __builtin_bit_cast(float, ua & 0xffff0000u)
                       + __builtin_bit_cast(float, ub & 0xffff0000u);
                dd[i] = (ua >> 16) | (ub & 0xffff0000u);
            }
#pragma unroll
            for (int i = 0; i < 8; ++i) ee[i] = (uint)__shfl_xor((int)dd[i], 32);
            // build B-frags for the two 16-krow MFMA steps of this half
#pragma unroll
            for (int s = 0; s < 2; ++s) {
                union { uint u[4]; bf16x8 v; } B;
                B.u[0] = lhi ? ee[4 * s + 2] : dd[4 * s + 0];
                B.u[1] = lhi ? ee[4 * s + 3] : dd[4 * s + 1];
                B.u[2] = lhi ? dd[4 * s + 2] : ee[4 * s + 0];
                B.u[3] = lhi ? dd[4 * s + 3] : ee[4 * s + 1];
                const int step = ms * 2 + s;
                bf16x8 va0 = *(const bf16x8*)&Vs[l31][step * 16 + lhi * 8];
                bf16x8 va1 = *(const bf16x8*)&Vs[32 + l31][step * 16 + lhi * 8];
                accO[0] = __builtin_amdgcn_mfma_f32_32x32x16_bf16(va0, B.v, accO[0], 0, 0, 0);
                accO[1] = __builtin_amdgcn_mfma_f32_32x32x16_bf16(va1, B.v, accO[1], 0, 0, 0);
            }
        }
    }

    // full l per qrow: krow halves live on lane^32 pairs
    const float lfull = lpart + __shfl_xor(lpart, 32);

    if (NSLICE == 1) {
        const float inv = 1.0f / lfull;
#pragma unroll
        for (int hf = 0; hf < 2; ++hf)
#pragma unroll
            for (int r = 0; r < 16; ++r) {
                const int d = (r & 3) + 8 * (r >> 2) + 4 * lhi + 32 * hf;
                AO[((size_t)(b * NSEQ + tok)) * 512 + h * 64 + d] =
                    (ushort_t)f2bf(accO[hf][r] * inv);
            }
    } else {
        if (lane < 32) Lp[(size_t)slice * 65536 + bh * 2048 + tok] = lfull;
        float* Os = Op + (size_t)slice * 4194304;
#pragma unroll
        for (int hf = 0; hf < 2; ++hf)
#pragma unroll
            for (int r = 0; r < 16; ++r) {
                const int d = (r & 3) + 8 * (r >> 2) + 4 * lhi + 32 * hf;
                Os[((size_t)(bh * 64 + d)) * 2048 + tok] = accO[hf][r];
            }
    }
}

// ---------------------------------------------------------------------------
// Combine split-K partials (transposed layout): AO[tok][e] = sum_s O_s / sum_s l_s.
// Reads Opart[s][bh*64+d][tok] coalesced, LDS-transposes 64x64, writes
// row-major bf16 coalesced.
// ---------------------------------------------------------------------------
__global__ __launch_bounds__(256)
void combine2T(const float* __restrict__ Op, const float* __restrict__ Lp,
               ushort_t* __restrict__ AO) {
    __shared__ float T[64][68];
    const int tid = threadIdx.x;
    const int tc = blockIdx.x, bh = blockIdx.y;
    const int b = bh >> 3, h = bh & 7;
    const int tok0 = tc * 64;

    const int d = tid >> 2, ts = (tid & 3) * 16;
    const float* P0 = Op + ((size_t)(bh * 64 + d)) * 2048 + tok0 + ts;
    const float* P1 = P0 + 4194304;
#pragma unroll
    for (int k = 0; k < 4; ++k) {
        f32x4 a = *(const f32x4*)(P0 + 4 * k);
        f32x4 c = *(const f32x4*)(P1 + 4 * k);
        *(f32x4*)&T[d][ts + 4 * k] = a + c;
    }
    __syncthreads();

    const int tk = tid >> 2, ds = (tid & 3) * 16;
    const int tok = tok0 + tk;
    const float inv = 1.0f / (Lp[bh * 2048 + tok] + Lp[65536 + bh * 2048 + tok]);
    uint o[8];
#pragma unroll
    for (int k = 0; k < 8; ++k) {
        float a = T[ds + 2 * k][tk] * inv;
        float c = T[ds + 2 * k + 1][tk] * inv;
        o[k] = f2bf(a) | (f2bf(c) << 16);
    }
    ushort_t* dst = AO + ((size_t)(b * NSEQ + tok)) * 512 + h * 64 + ds;
    *(uint4*)dst       = *(const uint4*)&o[0];
    *(uint4*)(dst + 8) = *(const uint4*)&o[4];
}

// ---------------------------------------------------------------------------
extern "C" void kernel_launch(void* const* d_in, const int* in_sizes, int n_in,
                              void* d_out, int out_size, void* d_ws, size_t ws_size,
                              hipStream_t stream) {
    const float* x  = (const float*)d_in[0];
    const float* Wq = (const float*)d_in[1];
    const float* bq = (const float*)d_in[2];
    const float* Wk = (const float*)d_in[3];
    const float* bk = (const float*)d_in[4];
    const float* Wv = (const float*)d_in[5];
    const float* bv = (const float*)d_in[6];
    const float* Wo = (const float*)d_in[7];
    const float* bo = (const float*)d_in[8];

    char* ws = (char*)d_ws;
    ushort_t* xb    = (ushort_t*)(ws);                       //  8,388,608 B
    ushort_t* Wqkvb = (ushort_t*)(ws + 8388608);             //  1,572,864 B
    ushort_t* Wob   = (ushort_t*)(ws + 9961472);             //    524,288 B
    float*    bqkv  = (float*)   (ws + 10485760);            //      6,144 B
    ushort_t* QKb   = (ushort_t*)(ws + 10491904);            // 16,777,216 B
    ushort_t* VTg   = (ushort_t*)(ws + 27269120);            //  8,388,608 B
    ushort_t* AOb   = (ushort_t*)(ws + 35657728);            //  8,388,608 B
    float*    Opart = (float*)   (ws + 44046336);            // 33,554,432 B
    float*    Lpart = (float*)   (ws + 77600768);            //    524,288 B
    const bool split = ws_size >= 78125056;

    prep<<<4096, 256, 0, stream>>>(x, Wq, Wk, Wv, Wo, bq, bk, bv,
                                   xb, Wqkvb, bqkv, Wob);
    gemm128<0><<<dim3(64, 12), 256, 0, stream>>>(xb, Wqkvb, bqkv, QKb, VTg, nullptr);
    if (split) {
        attn_mfma<2><<<dim3(16, 32, 2), 256, 0, stream>>>(QKb, VTg, Opart, Lpart, nullptr);
        combine2T<<<dim3(32, 32), 256, 0, stream>>>(Opart, Lpart, AOb);
    } else {
        attn_mfma<1><<<dim3(16, 32, 1), 256, 0, stream>>>(QKb, VTg, nullptr, nullptr, AOb);
    }
    gemm128<1><<<dim3(64, 4), 256, 0, stream>>>(AOb, Wob, bo, nullptr, nullptr, (float*)d_out);
}

// Round 6
// 187.492 us; speedup vs baseline: 1.9696x; 1.0003x over previous
//
#include <hip/hip_runtime.h>

typedef float f32x4 __attribute__((ext_vector_type(4)));
typedef float f32x16 __attribute__((ext_vector_type(16)));
typedef short bf16x8 __attribute__((ext_vector_type(8)));
typedef unsigned int uint;
typedef unsigned short ushort_t;

#define EMB    512
#define NSEQ   2048
#define NBATCH 4
#define NHEAD  8
#define MROWS  (NBATCH * NSEQ)   // 8192
#define CEXP   0.06375872f       // log2(e) / sqrt(512)

// round-to-nearest-even fp32 -> bf16 (bit trick)
__device__ __forceinline__ uint f2bf(float x) {
    uint u = __builtin_bit_cast(uint, x);
    return (u + 0x7fffu + ((u >> 16) & 1u)) >> 16;
}

// async global->LDS, 16B per lane; LDS dest = wave-uniform base + lane*16
__device__ __forceinline__ void glds16(const void* g, void* l) {
    __builtin_amdgcn_global_load_lds(
        (const __attribute__((address_space(1))) uint*)g,
        (__attribute__((address_space(3))) uint*)l, 16, 0, 0);
}

// ---------------------------------------------------------------------------
// Prep: x -> bf16; Wq|Wk|Wv -> Wqkvb bf16 [1536][512]; biases concat; Wo -> bf16
// ---------------------------------------------------------------------------
__global__ __launch_bounds__(256)
void prep(const float* __restrict__ x,
          const float* __restrict__ Wq, const float* __restrict__ Wk,
          const float* __restrict__ Wv, const float* __restrict__ Wo,
          const float* __restrict__ bq, const float* __restrict__ bk,
          const float* __restrict__ bv,
          ushort_t* __restrict__ xb, ushort_t* __restrict__ Wqkvb,
          float* __restrict__ bqkv, ushort_t* __restrict__ Wob) {
    int t = blockIdx.x * 256 + threadIdx.x;   // f4-group index, 1048576 total
    {
        float4 v = ((const float4*)x)[t];
        uint2 p;
        p.x = f2bf(v.x) | (f2bf(v.y) << 16);
        p.y = f2bf(v.z) | (f2bf(v.w) << 16);
        ((uint2*)xb)[t] = p;
    }
    if (t < 65536) {   // 512*512/4 groups per weight
        float4 a = ((const float4*)Wq)[t];
        float4 b = ((const float4*)Wk)[t];
        float4 c = ((const float4*)Wv)[t];
        float4 d = ((const float4*)Wo)[t];
        uint2 p;
        p.x = f2bf(a.x) | (f2bf(a.y) << 16); p.y = f2bf(a.z) | (f2bf(a.w) << 16);
        ((uint2*)Wqkvb)[t] = p;
        p.x = f2bf(b.x) | (f2bf(b.y) << 16); p.y = f2bf(b.z) | (f2bf(b.w) << 16);
        ((uint2*)Wqkvb)[t + 65536] = p;
        p.x = f2bf(c.x) | (f2bf(c.y) << 16); p.y = f2bf(c.z) | (f2bf(c.w) << 16);
        ((uint2*)Wqkvb)[t + 131072] = p;
        p.x = f2bf(d.x) | (f2bf(d.y) << 16); p.y = f2bf(d.z) | (f2bf(d.w) << 16);
        ((uint2*)Wob)[t] = p;
    }
    if (t < 512) {
        bqkv[t] = bq[t]; bqkv[512 + t] = bk[t]; bqkv[1024 + t] = bv[t];
    }
}

// ---------------------------------------------------------------------------
// GEMM C[8192 x N] = A[8192x512]bf16 * BT[Nx512]bf16 + bias, 128x128 tile,
// BK=32, 4 waves, 16x16x32 mfma, 4x4 subtiles/wave.
// Staging via global_load_lds width=16 (m97 pattern): unpadded [128][32]
// tiles, wave covers 16 rows per 1KB instruction, 2 instructions per matrix.
// MODE 0: QKV (N=1536): n0<1024 -> LDS-transposed coalesced bf16 stores to
//         QKb[8192][1024] (Q cols pre-scaled by CEXP);
//         n0>=1024 -> transposed packed stores to VTg[2048][2048].
// MODE 1: out proj (N=512): LDS-transposed coalesced fp32 stores + bias.
// ---------------------------------------------------------------------------
template<int MODE>
__global__ __launch_bounds__(256)
void gemm128(const ushort_t* __restrict__ A, const ushort_t* __restrict__ BT,
             const float* __restrict__ bias, ushort_t* __restrict__ oQK,
             ushort_t* __restrict__ oVT, float* __restrict__ oC) {
    __shared__ ushort_t As[128][32];   // 8 KB, unpadded (glds layout constraint)
    __shared__ ushort_t Bs[128][32];
    __shared__ float ep[32][132];      // epilogue transpose buffer (16.9 KB)
    const int tid = threadIdx.x, wave = tid >> 6, lane = tid & 63;
    const int m0 = blockIdx.x * 128, n0 = blockIdx.y * 128;
    const int wr = (wave & 1) * 64, wc = (wave >> 1) * 64;

    f32x4 acc[4][4];
#pragma unroll
    for (int i = 0; i < 4; ++i)
#pragma unroll
        for (int j = 0; j < 4; ++j) acc[i][j] = (f32x4){0.f, 0.f, 0.f, 0.f};

    // per-lane global source: row = wave*16 + lane/4, col-seg = (lane&3)*16B
    const int grow = wave * 16 + (lane >> 2);
    const int gcol = (lane & 3) * 8;
    const ushort_t* Ag = A  + (size_t)(m0 + grow) * 512 + gcol;
    const ushort_t* Bg = BT + (size_t)(n0 + grow) * 512 + gcol;
    ushort_t* lA0 = &As[wave * 16][0];
    ushort_t* lA1 = &As[64 + wave * 16][0];
    ushort_t* lB0 = &Bs[wave * 16][0];
    ushort_t* lB1 = &Bs[64 + wave * 16][0];
    const int fr = lane & 15, fc = (lane >> 4) * 8;

    for (int kt = 0; kt < 16; ++kt) {
        __syncthreads();   // prior frag reads done before overwrite
        glds16(Ag + kt * 32,             lA0);
        glds16(Ag + kt * 32 + 64 * 512,  lA1);
        glds16(Bg + kt * 32,             lB0);
        glds16(Bg + kt * 32 + 64 * 512,  lB1);
        __syncthreads();   // vmcnt(0) drained -> tiles visible
        bf16x8 af[4], bf[4];
#pragma unroll
        for (int i = 0; i < 4; ++i) af[i] = *(const bf16x8*)&As[wr + i * 16 + fr][fc];
#pragma unroll
        for (int j = 0; j < 4; ++j) bf[j] = *(const bf16x8*)&Bs[wc + j * 16 + fr][fc];
#pragma unroll
        for (int i = 0; i < 4; ++i)
#pragma unroll
            for (int j = 0; j < 4; ++j)
                acc[i][j] = __builtin_amdgcn_mfma_f32_16x16x32_bf16(af[i], bf[j], acc[i][j], 0, 0, 0);
    }

    const int col_l = lane & 15, row_l = (lane >> 4) * 4;

    if (MODE == 0 && n0 >= 1024) {
        // V part: direct transposed packed stores
#pragma unroll
        for (int j = 0; j < 4; ++j) {
            const int col = n0 + wc + j * 16 + col_l;
            const float bv = bias[col];
#pragma unroll
            for (int i = 0; i < 4; ++i) {
                const int row = m0 + wr + i * 16 + row_l;
                f32x4 v = acc[i][j];
                v += (f32x4){bv, bv, bv, bv};
                const int e = col - 1024;
                const int b = row >> 11, tok = row & 2047;
                uint2 p;
                p.x = f2bf(v[0]) | (f2bf(v[1]) << 16);
                p.y = f2bf(v[2]) | (f2bf(v[3]) << 16);
                *(uint2*)&oVT[((size_t)(b * 512 + e)) * 2048 + tok] = p;
            }
        }
        return;
    }

    // LDS-transposed coalesced epilogue (QK bf16 / out-proj fp32)
    const float scale = (MODE == 0 && n0 < 512) ? CEXP : 1.0f;
    float bv[4];
#pragma unroll
    for (int j = 0; j < 4; ++j) bv[j] = bias[n0 + wc + j * 16 + col_l];

    const int erow = tid >> 3, eseg = (tid & 7) * 16;
#pragma unroll
    for (int c = 0; c < 4; ++c) {
        __syncthreads();
        if (wr == (c >> 1) * 64) {
#pragma unroll
            for (int ii = 0; ii < 2; ++ii) {
                const int i = (c & 1) * 2 + ii;
#pragma unroll
                for (int j = 0; j < 4; ++j) {
                    f32x4 v = acc[i][j];
#pragma unroll
                    for (int r = 0; r < 4; ++r)
                        ep[ii * 16 + row_l + r][wc + j * 16 + col_l] = (v[r] + bv[j]) * scale;
                }
            }
        }
        __syncthreads();
        const int grow2 = m0 + c * 32 + erow;
        if (MODE == 0) {
            uint4 o0, o1;
#pragma unroll
            for (int k = 0; k < 4; ++k) {
                uint lo = f2bf(ep[erow][eseg + k * 2])     | (f2bf(ep[erow][eseg + k * 2 + 1]) << 16);
                uint hi = f2bf(ep[erow][eseg + 8 + k * 2]) | (f2bf(ep[erow][eseg + 9 + k * 2]) << 16);
                ((uint*)&o0)[k] = lo; ((uint*)&o1)[k] = hi;
            }
            *(uint4*)&oQK[(size_t)grow2 * 1024 + n0 + eseg]     = o0;
            *(uint4*)&oQK[(size_t)grow2 * 1024 + n0 + eseg + 8] = o1;
        } else {
#pragma unroll
            for (int k = 0; k < 4; ++k) {
                f32x4 v = *(const f32x4*)&ep[erow][eseg + k * 4];
                *(f32x4*)&oC[(size_t)grow2 * 512 + n0 + eseg + k * 4] = v;
            }
        }
    }
}

// ---------------------------------------------------------------------------
// MFMA flash attention, O^T formulation (no P LDS round-trip).
// Structure identical to round 5 (proven 52-VGPR, no spill); only the K-range
// split factor and the partial dtype changed.
// 256 threads / 4 waves, 128-row q-tile, __launch_bounds__(256,4).
// Per 64-krow tile, per krow-half ms: S^T = K*Q^T (32x32x16, C-layout:
// qrow=lane&31, krow=(r&3)+8*(r>>2)+4*lhi); P^T = exp2(S^T) trunc-bf16 packed
// in regs; B-frags for O^T += V^T * P^T built via pack + shfl_xor(32) swap.
// l sums truncated P (normalization bias cancels). NSLICE>1: unnormalized
// bf16 partials, transposed Opart[slice][bh*64+d][tok]; l partials fp32.
// ---------------------------------------------------------------------------
template<int NSLICE>
__global__ __launch_bounds__(256, 4)
void attn_mfma(const ushort_t* __restrict__ QK, const ushort_t* __restrict__ VT,
               ushort_t* __restrict__ Op, float* __restrict__ Lp,
               ushort_t* __restrict__ AO) {
    __shared__ ushort_t Ks[64][72];       // [krow][d]
    __shared__ ushort_t Vs[64][72];       // [d][krow]  (V^T tile)

    const int tid = threadIdx.x, w = tid >> 6, lane = tid & 63;
    const int qt = blockIdx.x, bh = blockIdx.y, b = bh >> 3, h = bh & 7;
    const int slice = (NSLICE > 1) ? blockIdx.z : 0;
    const int l31 = lane & 31, lhi = lane >> 5;

    // Q B-frags (pre-scaled by CEXP in gemm epilogue)
    const int tok = qt * 128 + w * 32 + l31;
    const size_t qrow = (size_t)(b * NSEQ + tok);
    bf16x8 qf[4];
#pragma unroll
    for (int ks = 0; ks < 4; ++ks)
        qf[ks] = *(const bf16x8*)&QK[qrow * 1024 + h * 64 + ks * 16 + lhi * 8];

    f32x16 accO[2];
#pragma unroll
    for (int i = 0; i < 16; ++i) { accO[0][i] = 0.f; accO[1][i] = 0.f; }
    float lpart = 0.f;

    // staging: 256 threads, 2 x uint4 per matrix per thread
    const int sr = tid & 63, sc = (tid >> 6) * 16;
    const ushort_t* Kg = QK + (size_t)(b * NSEQ) * 1024 + 512 + h * 64;
    const ushort_t* Vg = VT + ((size_t)(b * 512 + h * 64)) * 2048;

    const int kt0 = slice * (32 / NSLICE), kt1 = kt0 + 32 / NSLICE;
    for (int kt = kt0; kt < kt1; ++kt) {
        const int k0 = kt * 64;
        uint4 kv0 = *(const uint4*)&Kg[(size_t)(k0 + sr) * 1024 + sc];
        uint4 kv1 = *(const uint4*)&Kg[(size_t)(k0 + sr) * 1024 + sc + 8];
        uint4 vv0 = *(const uint4*)&Vg[(size_t)sr * 2048 + k0 + sc];
        uint4 vv1 = *(const uint4*)&Vg[(size_t)sr * 2048 + k0 + sc + 8];
        __syncthreads();                          // prior frag reads done
        *(uint4*)&Ks[sr][sc] = kv0;  *(uint4*)&Ks[sr][sc + 8] = kv1;
        *(uint4*)&Vs[sr][sc] = vv0;  *(uint4*)&Vs[sr][sc + 8] = vv1;
        __syncthreads();                          // tiles visible

#pragma unroll
        for (int ms = 0; ms < 2; ++ms) {   // krow halves 0..31 / 32..63
            // S^T half: A = K rows [ms*32 + l31], B = Q^T
            f32x16 st;
#pragma unroll
            for (int i = 0; i < 16; ++i) st[i] = 0.f;
#pragma unroll
            for (int ks = 0; ks < 4; ++ks) {
                bf16x8 ka = *(const bf16x8*)&Ks[ms * 32 + l31][ks * 16 + lhi * 8];
                st = __builtin_amdgcn_mfma_f32_32x32x16_bf16(ka, qf[ks], st, 0, 0, 0);
            }
            // P^T: exp2, truncate to bf16, pack pairs; l sums truncated values
            uint dd[8], ee[8];
#pragma unroll
            for (int i = 0; i < 8; ++i) {
                uint ua = __builtin_bit_cast(uint, __builtin_amdgcn_exp2f(st[2 * i]));
                uint ub = __builtin_bit_cast(uint, __builtin_amdgcn_exp2f(st[2 * i + 1]));
                lpart += __builtin_bit_cast(float, ua & 0xffff0000u)
                       + __builtin_bit_cast(float, ub & 0xffff0000u);
                dd[i] = (ua >> 16) | (ub & 0xffff0000u);
            }
#pragma unroll
            for (int i = 0; i < 8; ++i) ee[i] = (uint)__shfl_xor((int)dd[i], 32);
            // build B-frags for the two 16-krow MFMA steps of this half
#pragma unroll
            for (int s = 0; s < 2; ++s) {
                union { uint u[4]; bf16x8 v; } B;
                B.u[0] = lhi ? ee[4 * s + 2] : dd[4 * s + 0];
                B.u[1] = lhi ? ee[4 * s + 3] : dd[4 * s + 1];
                B.u[2] = lhi ? dd[4 * s + 2] : ee[4 * s + 0];
                B.u[3] = lhi ? dd[4 * s + 3] : ee[4 * s + 1];
                const int step = ms * 2 + s;
                bf16x8 va0 = *(const bf16x8*)&Vs[l31][step * 16 + lhi * 8];
                bf16x8 va1 = *(const bf16x8*)&Vs[32 + l31][step * 16 + lhi * 8];
                accO[0] = __builtin_amdgcn_mfma_f32_32x32x16_bf16(va0, B.v, accO[0], 0, 0, 0);
                accO[1] = __builtin_amdgcn_mfma_f32_32x32x16_bf16(va1, B.v, accO[1], 0, 0, 0);
            }
        }
    }

    // full l per qrow: krow halves live on lane^32 pairs
    const float lfull = lpart + __shfl_xor(lpart, 32);

    if (NSLICE == 1) {
        const float inv = 1.0f / lfull;
#pragma unroll
        for (int hf = 0; hf < 2; ++hf)
#pragma unroll
            for (int r = 0; r < 16; ++r) {
                const int d = (r & 3) + 8 * (r >> 2) + 4 * lhi + 32 * hf;
                AO[((size_t)(b * NSEQ + tok)) * 512 + h * 64 + d] =
                    (ushort_t)f2bf(accO[hf][r] * inv);
            }
    } else {
        if (lane < 32) Lp[(size_t)slice * 65536 + bh * 2048 + tok] = lfull;
        ushort_t* Os = Op + (size_t)slice * 4194304;
#pragma unroll
        for (int hf = 0; hf < 2; ++hf)
#pragma unroll
            for (int r = 0; r < 16; ++r) {
                const int d = (r & 3) + 8 * (r >> 2) + 4 * lhi + 32 * hf;
                Os[((size_t)(bh * 64 + d)) * 2048 + tok] = (ushort_t)f2bf(accO[hf][r]);
            }
    }
}

// ---------------------------------------------------------------------------
// Combine 4 split-K bf16 partials: AO[tok][e] = sum_s O_s / sum_s l_s.
// Reads Opart[s][bh*64+d][tok] coalesced (uint4 = 8 bf16), accumulates fp32,
// LDS-transposes 64x64, writes row-major bf16 coalesced.
// ---------------------------------------------------------------------------
__global__ __launch_bounds__(256)
void combine4T(const ushort_t* __restrict__ Op, const float* __restrict__ Lp,
               ushort_t* __restrict__ AO) {
    __shared__ float T[64][68];
    const int tid = threadIdx.x;
    const int tc = blockIdx.x, bh = blockIdx.y;
    const int b = bh >> 3, h = bh & 7;
    const int tok0 = tc * 64;

    const int d = tid >> 2, ts = (tid & 3) * 16;
    float acc[16];
#pragma unroll
    for (int i = 0; i < 16; ++i) acc[i] = 0.f;
#pragma unroll
    for (int s = 0; s < 4; ++s) {
        const ushort_t* P = Op + (size_t)s * 4194304
                               + ((size_t)(bh * 64 + d)) * 2048 + tok0 + ts;
#pragma unroll
        for (int k2 = 0; k2 < 2; ++k2) {
            uint4 u = *(const uint4*)(P + 8 * k2);
#pragma unroll
            for (int j = 0; j < 4; ++j) {
                uint uw = ((const uint*)&u)[j];
                acc[k2 * 8 + 2 * j]     += __builtin_bit_cast(float, uw << 16);
                acc[k2 * 8 + 2 * j + 1] += __builtin_bit_cast(float, uw & 0xffff0000u);
            }
        }
    }
#pragma unroll
    for (int k = 0; k < 4; ++k)
        *(f32x4*)&T[d][ts + 4 * k] = *(const f32x4*)&acc[4 * k];
    __syncthreads();

    const int tk = tid >> 2, ds = (tid & 3) * 16;
    const int tok = tok0 + tk;
    const float l = Lp[bh * 2048 + tok]           + Lp[65536 + bh * 2048 + tok]
                  + Lp[131072 + bh * 2048 + tok]  + Lp[196608 + bh * 2048 + tok];
    const float inv = 1.0f / l;
    uint o[8];
#pragma unroll
    for (int k = 0; k < 8; ++k) {
        float a = T[ds + 2 * k][tk] * inv;
        float c = T[ds + 2 * k + 1][tk] * inv;
        o[k] = f2bf(a) | (f2bf(c) << 16);
    }
    ushort_t* dst = AO + ((size_t)(b * NSEQ + tok)) * 512 + h * 64 + ds;
    *(uint4*)dst       = *(const uint4*)&o[0];
    *(uint4*)(dst + 8) = *(const uint4*)&o[4];
}

// ---------------------------------------------------------------------------
extern "C" void kernel_launch(void* const* d_in, const int* in_sizes, int n_in,
                              void* d_out, int out_size, void* d_ws, size_t ws_size,
                              hipStream_t stream) {
    const float* x  = (const float*)d_in[0];
    const float* Wq = (const float*)d_in[1];
    const float* bq = (const float*)d_in[2];
    const float* Wk = (const float*)d_in[3];
    const float* bk = (const float*)d_in[4];
    const float* Wv = (const float*)d_in[5];
    const float* bv = (const float*)d_in[6];
    const float* Wo = (const float*)d_in[7];
    const float* bo = (const float*)d_in[8];

    char* ws = (char*)d_ws;
    ushort_t* xb    = (ushort_t*)(ws);                       //  8,388,608 B
    ushort_t* Wqkvb = (ushort_t*)(ws + 8388608);             //  1,572,864 B
    ushort_t* Wob   = (ushort_t*)(ws + 9961472);             //    524,288 B
    float*    bqkv  = (float*)   (ws + 10485760);            //      6,144 B
    ushort_t* QKb   = (ushort_t*)(ws + 10491904);            // 16,777,216 B
    ushort_t* VTg   = (ushort_t*)(ws + 27269120);            //  8,388,608 B
    ushort_t* AOb   = (ushort_t*)(ws + 35657728);            //  8,388,608 B
    ushort_t* Opart = (ushort_t*)(ws + 44046336);            // 33,554,432 B (4 slices bf16)
    float*    Lpart = (float*)   (ws);                       //  1,048,576 B overlay on xb
                                                             //  (xb dead after gemm<0>)
    const bool split = ws_size >= 78125056;

    prep<<<4096, 256, 0, stream>>>(x, Wq, Wk, Wv, Wo, bq, bk, bv,
                                   xb, Wqkvb, bqkv, Wob);
    gemm128<0><<<dim3(64, 12), 256, 0, stream>>>(xb, Wqkvb, bqkv, QKb, VTg, nullptr);
    if (split) {
        attn_mfma<4><<<dim3(16, 32, 4), 256, 0, stream>>>(QKb, VTg, Opart, Lpart, nullptr);
        combine4T<<<dim3(32, 32), 256, 0, stream>>>(Opart, Lpart, AOb);
    } else {
        attn_mfma<1><<<dim3(16, 32, 1), 256, 0, stream>>>(QKb, VTg, nullptr, nullptr, AOb);
    }
    gemm128<1><<<dim3(64, 4), 256, 0, stream>>>(AOb, Wob, bo, nullptr, nullptr, (float*)d_out);
}

// Round 7
// 183.266 us; speedup vs baseline: 2.0150x; 1.0231x over previous
//
#include <hip/hip_runtime.h>

typedef float f32x4 __attribute__((ext_vector_type(4)));
typedef float f32x16 __attribute__((ext_vector_type(16)));
typedef short bf16x8 __attribute__((ext_vector_type(8)));
typedef unsigned int uint;
typedef unsigned short ushort_t;

#define EMB    512
#define NSEQ   2048
#define NBATCH 4
#define NHEAD  8
#define MROWS  (NBATCH * NSEQ)   // 8192
#define CEXP   0.06375872f       // log2(e) / sqrt(512)

// round-to-nearest-even fp32 -> bf16 (bit trick)
__device__ __forceinline__ uint f2bf(float x) {
    uint u = __builtin_bit_cast(uint, x);
    return (u + 0x7fffu + ((u >> 16) & 1u)) >> 16;
}

// async global->LDS, 16B per lane; LDS dest = wave-uniform base + lane*16
__device__ __forceinline__ void glds16(const void* g, void* l) {
    __builtin_amdgcn_global_load_lds(
        (const __attribute__((address_space(1))) uint*)g,
        (__attribute__((address_space(3))) uint*)l, 16, 0, 0);
}

// ---------------------------------------------------------------------------
// Prep: x -> bf16; Wq|Wk|Wv -> Wqkvb bf16 [1536][512]; biases concat; Wo -> bf16
// ---------------------------------------------------------------------------
__global__ __launch_bounds__(256)
void prep(const float* __restrict__ x,
          const float* __restrict__ Wq, const float* __restrict__ Wk,
          const float* __restrict__ Wv, const float* __restrict__ Wo,
          const float* __restrict__ bq, const float* __restrict__ bk,
          const float* __restrict__ bv,
          ushort_t* __restrict__ xb, ushort_t* __restrict__ Wqkvb,
          float* __restrict__ bqkv, ushort_t* __restrict__ Wob) {
    int t = blockIdx.x * 256 + threadIdx.x;   // f4-group index, 1048576 total
    {
        float4 v = ((const float4*)x)[t];
        uint2 p;
        p.x = f2bf(v.x) | (f2bf(v.y) << 16);
        p.y = f2bf(v.z) | (f2bf(v.w) << 16);
        ((uint2*)xb)[t] = p;
    }
    if (t < 65536) {   // 512*512/4 groups per weight
        float4 a = ((const float4*)Wq)[t];
        float4 b = ((const float4*)Wk)[t];
        float4 c = ((const float4*)Wv)[t];
        float4 d = ((const float4*)Wo)[t];
        uint2 p;
        p.x = f2bf(a.x) | (f2bf(a.y) << 16); p.y = f2bf(a.z) | (f2bf(a.w) << 16);
        ((uint2*)Wqkvb)[t] = p;
        p.x = f2bf(b.x) | (f2bf(b.y) << 16); p.y = f2bf(b.z) | (f2bf(b.w) << 16);
        ((uint2*)Wqkvb)[t + 65536] = p;
        p.x = f2bf(c.x) | (f2bf(c.y) << 16); p.y = f2bf(c.z) | (f2bf(c.w) << 16);
        ((uint2*)Wqkvb)[t + 131072] = p;
        p.x = f2bf(d.x) | (f2bf(d.y) << 16); p.y = f2bf(d.z) | (f2bf(d.w) << 16);
        ((uint2*)Wob)[t] = p;
    }
    if (t < 512) {
        bqkv[t] = bq[t]; bqkv[512 + t] = bk[t]; bqkv[1024 + t] = bv[t];
    }
}

// ---------------------------------------------------------------------------
// GEMM C[8192 x N] = A[8192x512]bf16 * BT[Nx512]bf16 + bias, 128x128 tile,
// BK=32, 4 waves, 16x16x32 mfma, 4x4 subtiles/wave. glds16 staging (m97).
// MODE 0: QKV (N=1536): n0<1024 -> LDS-transposed coalesced bf16 stores to
//         QKb[8192][1024] (Q cols pre-scaled by CEXP);
//         n0>=1024 -> transposed packed stores to VTg[2048][2048].
// MODE 1: out proj (N=512): LDS-transposed coalesced fp32 stores + bias.
// ---------------------------------------------------------------------------
template<int MODE>
__global__ __launch_bounds__(256)
void gemm128(const ushort_t* __restrict__ A, const ushort_t* __restrict__ BT,
             const float* __restrict__ bias, ushort_t* __restrict__ oQK,
             ushort_t* __restrict__ oVT, float* __restrict__ oC) {
    __shared__ ushort_t As[128][32];   // 8 KB, unpadded (glds layout constraint)
    __shared__ ushort_t Bs[128][32];
    __shared__ float ep[32][132];      // epilogue transpose buffer (16.9 KB)
    const int tid = threadIdx.x, wave = tid >> 6, lane = tid & 63;
    const int m0 = blockIdx.x * 128, n0 = blockIdx.y * 128;
    const int wr = (wave & 1) * 64, wc = (wave >> 1) * 64;

    f32x4 acc[4][4];
#pragma unroll
    for (int i = 0; i < 4; ++i)
#pragma unroll
        for (int j = 0; j < 4; ++j) acc[i][j] = (f32x4){0.f, 0.f, 0.f, 0.f};

    const int grow = wave * 16 + (lane >> 2);
    const int gcol = (lane & 3) * 8;
    const ushort_t* Ag = A  + (size_t)(m0 + grow) * 512 + gcol;
    const ushort_t* Bg = BT + (size_t)(n0 + grow) * 512 + gcol;
    ushort_t* lA0 = &As[wave * 16][0];
    ushort_t* lA1 = &As[64 + wave * 16][0];
    ushort_t* lB0 = &Bs[wave * 16][0];
    ushort_t* lB1 = &Bs[64 + wave * 16][0];
    const int fr = lane & 15, fc = (lane >> 4) * 8;

    for (int kt = 0; kt < 16; ++kt) {
        __syncthreads();   // prior frag reads done before overwrite
        glds16(Ag + kt * 32,             lA0);
        glds16(Ag + kt * 32 + 64 * 512,  lA1);
        glds16(Bg + kt * 32,             lB0);
        glds16(Bg + kt * 32 + 64 * 512,  lB1);
        __syncthreads();   // vmcnt(0) drained -> tiles visible
        bf16x8 af[4], bf[4];
#pragma unroll
        for (int i = 0; i < 4; ++i) af[i] = *(const bf16x8*)&As[wr + i * 16 + fr][fc];
#pragma unroll
        for (int j = 0; j < 4; ++j) bf[j] = *(const bf16x8*)&Bs[wc + j * 16 + fr][fc];
#pragma unroll
        for (int i = 0; i < 4; ++i)
#pragma unroll
            for (int j = 0; j < 4; ++j)
                acc[i][j] = __builtin_amdgcn_mfma_f32_16x16x32_bf16(af[i], bf[j], acc[i][j], 0, 0, 0);
    }

    const int col_l = lane & 15, row_l = (lane >> 4) * 4;

    if (MODE == 0 && n0 >= 1024) {
        // V part: direct transposed packed stores
#pragma unroll
        for (int j = 0; j < 4; ++j) {
            const int col = n0 + wc + j * 16 + col_l;
            const float bv = bias[col];
#pragma unroll
            for (int i = 0; i < 4; ++i) {
                const int row = m0 + wr + i * 16 + row_l;
                f32x4 v = acc[i][j];
                v += (f32x4){bv, bv, bv, bv};
                const int e = col - 1024;
                const int b = row >> 11, tok = row & 2047;
                uint2 p;
                p.x = f2bf(v[0]) | (f2bf(v[1]) << 16);
                p.y = f2bf(v[2]) | (f2bf(v[3]) << 16);
                *(uint2*)&oVT[((size_t)(b * 512 + e)) * 2048 + tok] = p;
            }
        }
        return;
    }

    // LDS-transposed coalesced epilogue (QK bf16 / out-proj fp32)
    const float scale = (MODE == 0 && n0 < 512) ? CEXP : 1.0f;
    float bv[4];
#pragma unroll
    for (int j = 0; j < 4; ++j) bv[j] = bias[n0 + wc + j * 16 + col_l];

    const int erow = tid >> 3, eseg = (tid & 7) * 16;
#pragma unroll
    for (int c = 0; c < 4; ++c) {
        __syncthreads();
        if (wr == (c >> 1) * 64) {
#pragma unroll
            for (int ii = 0; ii < 2; ++ii) {
                const int i = (c & 1) * 2 + ii;
#pragma unroll
                for (int j = 0; j < 4; ++j) {
                    f32x4 v = acc[i][j];
#pragma unroll
                    for (int r = 0; r < 4; ++r)
                        ep[ii * 16 + row_l + r][wc + j * 16 + col_l] = (v[r] + bv[j]) * scale;
                }
            }
        }
        __syncthreads();
        const int grow2 = m0 + c * 32 + erow;
        if (MODE == 0) {
            uint4 o0, o1;
#pragma unroll
            for (int k = 0; k < 4; ++k) {
                uint lo = f2bf(ep[erow][eseg + k * 2])     | (f2bf(ep[erow][eseg + k * 2 + 1]) << 16);
                uint hi = f2bf(ep[erow][eseg + 8 + k * 2]) | (f2bf(ep[erow][eseg + 9 + k * 2]) << 16);
                ((uint*)&o0)[k] = lo; ((uint*)&o1)[k] = hi;
            }
            *(uint4*)&oQK[(size_t)grow2 * 1024 + n0 + eseg]     = o0;
            *(uint4*)&oQK[(size_t)grow2 * 1024 + n0 + eseg + 8] = o1;
        } else {
#pragma unroll
            for (int k = 0; k < 4; ++k) {
                f32x4 v = *(const f32x4*)&ep[erow][eseg + k * 4];
                *(f32x4*)&oC[(size_t)grow2 * 512 + n0 + eseg + k * 4] = v;
            }
        }
    }
}

// ---------------------------------------------------------------------------
// MFMA flash attention, O^T formulation; 64 q-rows PER WAVE (two 32-row
// groups) so ka/va LDS fragment reads are shared across 2x the MFMA work:
// LDS pipe + staging + barriers per FLOP halve vs the 32-row version.
// Block = 4 waves = 256 q-rows; grid (8, 32, NSLICE).
// Per 64-krow tile, per krow-half ms: ka[4] shared; st_g = K*Q_g^T chains;
// P^T = exp2(st) trunc-bf16 packed; B-frags via pack + shfl_xor(32) swap;
// O_g^T += V^T * P_g^T with va shared across g. l sums truncated P.
// accO (4 x f32x16) lives in AGPRs (unified file); VGPR peak ~110.
// ---------------------------------------------------------------------------
template<int NSLICE>
__global__ __launch_bounds__(256, 3)
void attn_mfma(const ushort_t* __restrict__ QK, const ushort_t* __restrict__ VT,
               ushort_t* __restrict__ Op, float* __restrict__ Lp,
               ushort_t* __restrict__ AO) {
    __shared__ ushort_t Ks[64][72];       // [krow][d]
    __shared__ ushort_t Vs[64][72];       // [d][krow]  (V^T tile)

    const int tid = threadIdx.x, w = tid >> 6, lane = tid & 63;
    const int qt = blockIdx.x, bh = blockIdx.y, b = bh >> 3, h = bh & 7;
    const int slice = (NSLICE > 1) ? blockIdx.z : 0;
    const int l31 = lane & 31, lhi = lane >> 5;

    // Q B-frags for both q-groups (pre-scaled by CEXP in gemm epilogue)
    const int tok0 = qt * 256 + w * 64 + l31;   // q-group g adds g*32
    bf16x8 qf[2][4];
#pragma unroll
    for (int g = 0; g < 2; ++g)
#pragma unroll
        for (int ks = 0; ks < 4; ++ks)
            qf[g][ks] = *(const bf16x8*)&QK[(size_t)(b * NSEQ + tok0 + g * 32) * 1024
                                            + h * 64 + ks * 16 + lhi * 8];

    f32x16 accO[2][2];   // [g][d-half] -> AGPRs
#pragma unroll
    for (int g = 0; g < 2; ++g)
#pragma unroll
        for (int i = 0; i < 16; ++i) { accO[g][0][i] = 0.f; accO[g][1][i] = 0.f; }
    float lpart[2] = {0.f, 0.f};

    // staging: 256 threads, 2 x uint4 per matrix per thread
    const int sr = tid & 63, sc = (tid >> 6) * 16;
    const ushort_t* Kg = QK + (size_t)(b * NSEQ) * 1024 + 512 + h * 64;
    const ushort_t* Vg = VT + ((size_t)(b * 512 + h * 64)) * 2048;

    const int kt0 = slice * (32 / NSLICE), kt1 = kt0 + 32 / NSLICE;
    for (int kt = kt0; kt < kt1; ++kt) {
        const int k0 = kt * 64;
        uint4 kv0 = *(const uint4*)&Kg[(size_t)(k0 + sr) * 1024 + sc];
        uint4 kv1 = *(const uint4*)&Kg[(size_t)(k0 + sr) * 1024 + sc + 8];
        uint4 vv0 = *(const uint4*)&Vg[(size_t)sr * 2048 + k0 + sc];
        uint4 vv1 = *(const uint4*)&Vg[(size_t)sr * 2048 + k0 + sc + 8];
        __syncthreads();                          // prior frag reads done
        *(uint4*)&Ks[sr][sc] = kv0;  *(uint4*)&Ks[sr][sc + 8] = kv1;
        *(uint4*)&Vs[sr][sc] = vv0;  *(uint4*)&Vs[sr][sc + 8] = vv1;
        __syncthreads();                          // tiles visible

#pragma unroll
        for (int ms = 0; ms < 2; ++ms) {   // krow halves 0..31 / 32..63
            // shared K fragments for this half
            bf16x8 ka[4];
#pragma unroll
            for (int ks = 0; ks < 4; ++ks)
                ka[ks] = *(const bf16x8*)&Ks[ms * 32 + l31][ks * 16 + lhi * 8];

            // S^T chains for both q-groups (share ka)
            f32x16 st[2];
#pragma unroll
            for (int g = 0; g < 2; ++g)
#pragma unroll
                for (int i = 0; i < 16; ++i) st[g][i] = 0.f;
#pragma unroll
            for (int ks = 0; ks < 4; ++ks) {
                st[0] = __builtin_amdgcn_mfma_f32_32x32x16_bf16(ka[ks], qf[0][ks], st[0], 0, 0, 0);
                st[1] = __builtin_amdgcn_mfma_f32_32x32x16_bf16(ka[ks], qf[1][ks], st[1], 0, 0, 0);
            }

            // P^T = exp2(S^T), truncate to bf16, pack; l sums truncated values
            uint dd[2][8], ee[2][8];
#pragma unroll
            for (int g = 0; g < 2; ++g)
#pragma unroll
                for (int i = 0; i < 8; ++i) {
                    uint ua = __builtin_bit_cast(uint, __builtin_amdgcn_exp2f(st[g][2 * i]));
                    uint ub = __builtin_bit_cast(uint, __builtin_amdgcn_exp2f(st[g][2 * i + 1]));
                    lpart[g] += __builtin_bit_cast(float, ua & 0xffff0000u)
                              + __builtin_bit_cast(float, ub & 0xffff0000u);
                    dd[g][i] = (ua >> 16) | (ub & 0xffff0000u);
                }
#pragma unroll
            for (int g = 0; g < 2; ++g)
#pragma unroll
                for (int i = 0; i < 8; ++i)
                    ee[g][i] = (uint)__shfl_xor((int)dd[g][i], 32);

            // PV: va shared across q-groups
#pragma unroll
            for (int s = 0; s < 2; ++s) {
                const int step = ms * 2 + s;
                bf16x8 va0 = *(const bf16x8*)&Vs[l31][step * 16 + lhi * 8];
                bf16x8 va1 = *(const bf16x8*)&Vs[32 + l31][step * 16 + lhi * 8];
#pragma unroll
                for (int g = 0; g < 2; ++g) {
                    union { uint u[4]; bf16x8 v; } B;
                    B.u[0] = lhi ? ee[g][4 * s + 2] : dd[g][4 * s + 0];
                    B.u[1] = lhi ? ee[g][4 * s + 3] : dd[g][4 * s + 1];
                    B.u[2] = lhi ? dd[g][4 * s + 2] : ee[g][4 * s + 0];
                    B.u[3] = lhi ? dd[g][4 * s + 3] : ee[g][4 * s + 1];
                    accO[g][0] = __builtin_amdgcn_mfma_f32_32x32x16_bf16(va0, B.v, accO[g][0], 0, 0, 0);
                    accO[g][1] = __builtin_amdgcn_mfma_f32_32x32x16_bf16(va1, B.v, accO[g][1], 0, 0, 0);
                }
            }
        }
    }

    // full l per qrow: krow halves live on lane^32 pairs
    float lfull[2];
#pragma unroll
    for (int g = 0; g < 2; ++g) lfull[g] = lpart[g] + __shfl_xor(lpart[g], 32);

    if (NSLICE == 1) {
#pragma unroll
        for (int g = 0; g < 2; ++g) {
            const float inv = 1.0f / lfull[g];
#pragma unroll
            for (int hf = 0; hf < 2; ++hf)
#pragma unroll
                for (int r = 0; r < 16; ++r) {
                    const int d = (r & 3) + 8 * (r >> 2) + 4 * lhi + 32 * hf;
                    AO[((size_t)(b * NSEQ + tok0 + g * 32)) * 512 + h * 64 + d] =
                        (ushort_t)f2bf(accO[g][hf][r] * inv);
                }
        }
    } else {
        if (lane < 32) {
#pragma unroll
            for (int g = 0; g < 2; ++g)
                Lp[(size_t)slice * 65536 + bh * 2048 + tok0 + g * 32] = lfull[g];
        }
        ushort_t* Os = Op + (size_t)slice * 4194304;
#pragma unroll
        for (int g = 0; g < 2; ++g)
#pragma unroll
            for (int hf = 0; hf < 2; ++hf)
#pragma unroll
                for (int r = 0; r < 16; ++r) {
                    const int d = (r & 3) + 8 * (r >> 2) + 4 * lhi + 32 * hf;
                    Os[((size_t)(bh * 64 + d)) * 2048 + tok0 + g * 32] =
                        (ushort_t)f2bf(accO[g][hf][r]);
                }
    }
}

// ---------------------------------------------------------------------------
// Combine 2 split-K bf16 partials: AO[tok][e] = sum_s O_s / sum_s l_s.
// Reads Opart[s][bh*64+d][tok] coalesced (uint4 = 8 bf16), accumulates fp32,
// LDS-transposes 64x64, writes row-major bf16 coalesced.
// ---------------------------------------------------------------------------
__global__ __launch_bounds__(256)
void combine2Tb(const ushort_t* __restrict__ Op, const float* __restrict__ Lp,
                ushort_t* __restrict__ AO) {
    __shared__ float T[64][68];
    const int tid = threadIdx.x;
    const int tc = blockIdx.x, bh = blockIdx.y;
    const int b = bh >> 3, h = bh & 7;
    const int tok0 = tc * 64;

    const int d = tid >> 2, ts = (tid & 3) * 16;
    float acc[16];
#pragma unroll
    for (int i = 0; i < 16; ++i) acc[i] = 0.f;
#pragma unroll
    for (int s = 0; s < 2; ++s) {
        const ushort_t* P = Op + (size_t)s * 4194304
                               + ((size_t)(bh * 64 + d)) * 2048 + tok0 + ts;
#pragma unroll
        for (int k2 = 0; k2 < 2; ++k2) {
            uint4 u = *(const uint4*)(P + 8 * k2);
#pragma unroll
            for (int j = 0; j < 4; ++j) {
                uint uw = ((const uint*)&u)[j];
                acc[k2 * 8 + 2 * j]     += __builtin_bit_cast(float, uw << 16);
                acc[k2 * 8 + 2 * j + 1] += __builtin_bit_cast(float, uw & 0xffff0000u);
            }
        }
    }
#pragma unroll
    for (int k = 0; k < 4; ++k)
        *(f32x4*)&T[d][ts + 4 * k] = *(const f32x4*)&acc[4 * k];
    __syncthreads();

    const int tk = tid >> 2, ds = (tid & 3) * 16;
    const int tok = tok0 + tk;
    const float inv = 1.0f / (Lp[bh * 2048 + tok] + Lp[65536 + bh * 2048 + tok]);
    uint o[8];
#pragma unroll
    for (int k = 0; k < 8; ++k) {
        float a = T[ds + 2 * k][tk] * inv;
        float c = T[ds + 2 * k + 1][tk] * inv;
        o[k] = f2bf(a) | (f2bf(c) << 16);
    }
    ushort_t* dst = AO + ((size_t)(b * NSEQ + tok)) * 512 + h * 64 + ds;
    *(uint4*)dst       = *(const uint4*)&o[0];
    *(uint4*)(dst + 8) = *(const uint4*)&o[4];
}

// ---------------------------------------------------------------------------
extern "C" void kernel_launch(void* const* d_in, const int* in_sizes, int n_in,
                              void* d_out, int out_size, void* d_ws, size_t ws_size,
                              hipStream_t stream) {
    const float* x  = (const float*)d_in[0];
    const float* Wq = (const float*)d_in[1];
    const float* bq = (const float*)d_in[2];
    const float* Wk = (const float*)d_in[3];
    const float* bk = (const float*)d_in[4];
    const float* Wv = (const float*)d_in[5];
    const float* bv = (const float*)d_in[6];
    const float* Wo = (const float*)d_in[7];
    const float* bo = (const float*)d_in[8];

    char* ws = (char*)d_ws;
    ushort_t* xb    = (ushort_t*)(ws);                       //  8,388,608 B
    ushort_t* Wqkvb = (ushort_t*)(ws + 8388608);             //  1,572,864 B
    ushort_t* Wob   = (ushort_t*)(ws + 9961472);             //    524,288 B
    float*    bqkv  = (float*)   (ws + 10485760);            //      6,144 B
    ushort_t* QKb   = (ushort_t*)(ws + 10491904);            // 16,777,216 B
    ushort_t* VTg   = (ushort_t*)(ws + 27269120);            //  8,388,608 B
    ushort_t* AOb   = (ushort_t*)(ws + 35657728);            //  8,388,608 B
    ushort_t* Opart = (ushort_t*)(ws + 44046336);            // 16,777,216 B (2 slices bf16)
    float*    Lpart = (float*)   (ws);                       //    524,288 B overlay on xb
                                                             //  (xb dead after gemm<0>)
    const bool split = ws_size >= 78125056;

    prep<<<4096, 256, 0, stream>>>(x, Wq, Wk, Wv, Wo, bq, bk, bv,
                                   xb, Wqkvb, bqkv, Wob);
    gemm128<0><<<dim3(64, 12), 256, 0, stream>>>(xb, Wqkvb, bqkv, QKb, VTg, nullptr);
    if (split) {
        attn_mfma<2><<<dim3(8, 32, 2), 256, 0, stream>>>(QKb, VTg, Opart, Lpart, nullptr);
        combine2Tb<<<dim3(32, 32), 256, 0, stream>>>(Opart, Lpart, AOb);
    } else {
        attn_mfma<1><<<dim3(8, 32, 1), 256, 0, stream>>>(QKb, VTg, nullptr, nullptr, AOb);
    }
    gemm128<1><<<dim3(64, 4), 256, 0, stream>>>(AOb, Wob, bo, nullptr, nullptr, (float*)d_out);
}